// Round 17
// baseline (667.832 us; speedup 1.0000x reference)
//
#include <hip/hip_runtime.h>
#include <stdint.h>

typedef unsigned short u16;
typedef short bf16x8 __attribute__((ext_vector_type(8)));
typedef float f32x4 __attribute__((ext_vector_type(4)));

__device__ __forceinline__ u16 f2b(float f) {
  uint32_t u = __builtin_bit_cast(uint32_t, f);
  u += 0x7fffu + ((u >> 16) & 1u);
  return (u16)(u >> 16);
}

// 2x f32 -> packed 2x bf16 (RNE), single VALU op (gfx950). lo -> bits[15:0].
__device__ __forceinline__ uint32_t cvtpk(float lo, float hi) {
  uint32_t r;
  asm("v_cvt_pk_bf16_f32 %0, %1, %2" : "=v"(r) : "v"(lo), "v"(hi));
  return r;
}

__device__ __forceinline__ void gload_lds16(const void* g, void* l) {
  __builtin_amdgcn_global_load_lds(
      (const __attribute__((address_space(1))) void*)g,
      (__attribute__((address_space(3))) void*)l, 16, 0, 0);
}

// ---------------- fp32 -> bf16, grid-stride (total elems = n8 * 8) ----------------
__global__ __launch_bounds__(256) void cvt_kernel(const float* __restrict__ src,
                                                  u16* __restrict__ dst, int n8) {
  int stride = gridDim.x * 256;
  for (int idx = blockIdx.x * 256 + threadIdx.x; idx < n8; idx += stride) {
    int64_t i = (int64_t)idx * 8;
    float4 a = *(const float4*)(src + i);
    float4 b = *(const float4*)(src + i + 4);
    union { u16 u[8]; bf16x8 v; } o;
    o.u[0] = f2b(a.x); o.u[1] = f2b(a.y); o.u[2] = f2b(a.z); o.u[3] = f2b(a.w);
    o.u[4] = f2b(b.x); o.u[5] = f2b(b.y); o.u[6] = f2b(b.z); o.u[7] = f2b(b.w);
    *(bf16x8*)(dst + i) = o.v;
  }
}

// ---- merged: 4x W [1024][1024] fp32 -> W^T bf16 (+ gate cumprod on block 0) ----
__global__ __launch_bounds__(256) void transpose_all_kernel(
    const float* __restrict__ Wk, const float* __restrict__ Wv,
    const float* __restrict__ Wfc, const float* __restrict__ Wq,
    u16* __restrict__ wkvT, u16* __restrict__ wfcT, u16* __restrict__ wqT,
    const float* __restrict__ gl, float* __restrict__ gate) {
  if (blockIdx.x == 0 && threadIdx.x == 0) {
    float g = 1.0f;
    for (int i = 0; i < 30; ++i) {
      float s = 1.0f / (1.0f + __expf(-gl[i]));
      g *= (1.0f - s);
      gate[i] = g;
    }
  }
  __shared__ float ls[64][65];
  int which = blockIdx.x >> 8;
  int tile = blockIdx.x & 255;
  const float* src = (which == 0) ? Wk : (which == 1) ? Wv : (which == 2) ? Wfc : Wq;
  u16* dst = (which == 0) ? wkvT : (which == 1) ? (wkvT + 1024 * 1024)
           : (which == 2) ? wfcT : wqT;
  int t = threadIdx.x;
  int bx = tile & 15;
  int by = tile >> 4;
  int r0 = by * 64, c0 = bx * 64;
  int tr = t >> 6, tc = t & 63;
#pragma unroll
  for (int i = 0; i < 16; ++i)
    ls[tr + i * 4][tc] = src[(int64_t)(r0 + tr + i * 4) * 1024 + c0 + tc];
  __syncthreads();
#pragma unroll
  for (int i = 0; i < 16; ++i)
    dst[(int64_t)(c0 + tr + i * 4) * 1024 + r0 + tc] = f2b(ls[tc][tr + i * 4]);
}

// ---------------- q GEMM: [64 x 1024] @ wqT -> qb [64][1024] (scaled) ----------------
__global__ __launch_bounds__(256, 4) void q_gemm_kernel(
    const u16* __restrict__ qtokb, const u16* __restrict__ wqT, u16* __restrict__ qb) {
  __shared__ u16 As[4096];  // [64][64]
  __shared__ u16 Bs[8192];  // [128][64]
  int n0 = blockIdx.x * 128;
  int t = threadIdx.x, w = t >> 6, lane = t & 63;
  int wn = w * 32;
  f32x4 acc[2][4] = {};
  int l3 = lane >> 3;
  int colE = ((lane & 7) ^ l3) * 8;
  const u16* aS = qtokb + (int64_t)(w * 16 + l3) * 1024 + colE;
  const u16* bS = wqT + (int64_t)(n0 + w * 32 + l3) * 1024 + colE;
  u16* aD = As + w * 1024;
  u16* bD = Bs + w * 2048;
  int l15 = lane & 15, g16 = lane >> 4;
  for (int kt = 0; kt < 16; ++kt) {
    int ko = kt * 64;
    __syncthreads();
    gload_lds16(aS + ko, aD);
    gload_lds16(aS + ko + 8192, aD + 512);
#pragma unroll
    for (int g = 0; g < 4; ++g) gload_lds16(bS + ko + g * 8192, bD + g * 512);
    __syncthreads();
#pragma unroll
    for (int kk = 0; kk < 2; ++kk) {
      int sl = ((kk * 4 + g16) ^ (l15 & 7)) * 8;
      bf16x8 af[4], bf[2];
#pragma unroll
      for (int j = 0; j < 4; ++j) af[j] = *(const bf16x8*)(As + (j * 16 + l15) * 64 + sl);
#pragma unroll
      for (int i = 0; i < 2; ++i) bf[i] = *(const bf16x8*)(Bs + (wn + i * 16 + l15) * 64 + sl);
#pragma unroll
      for (int i = 0; i < 2; ++i)
#pragma unroll
        for (int j = 0; j < 4; ++j)
          acc[i][j] = __builtin_amdgcn_mfma_f32_16x16x32_bf16(bf[i], af[j], acc[i][j], 0, 0, 0);
    }
  }
  const float sc = 1.44269504f / 8.0f;  // log2e / sqrt(dk)
  int lr = g16 * 4;
#pragma unroll
  for (int i = 0; i < 2; ++i) {
    int colg = n0 + wn + i * 16 + lr;
#pragma unroll
    for (int j = 0; j < 4; ++j) {
      int qrow = j * 16 + l15;
      u16 p[4];
#pragma unroll
      for (int r = 0; r < 4; ++r) p[r] = f2b(acc[i][j][r] * sc);
      *(uint64_t*)(qb + qrow * 1024 + colg) = *(uint64_t*)p;
    }
  }
}

// ---------------- KV GEMM (cvt-fused): [65536 x 1024 fp32] @ [1024 x 2048] ----------------
// R16 state (~500 us): A reg-staged with v_cvt_pk_bf16_f32 (T14 issue-early),
// B gload_lds, XCD-grouped mapping, (256,2). Structure closed per R7-R12 sweep.
__global__ __launch_bounds__(256, 2) void kv_gemm_kernel(
    const float* __restrict__ x, const u16* __restrict__ wkvT,
    const float* __restrict__ gate, u16* __restrict__ kbuf, u16* __restrict__ vT) {
  __shared__ u16 As[8192];  // [128][64]
  __shared__ u16 Bs[8192];
  int d = blockIdx.x;
  int xc = d & 7;
  int nb = (d >> 3) & 15;
  int mb = (d >> 7) * 8 + xc;
  int m0 = mb * 128, n0 = nb * 128;
  int t = threadIdx.x, w = t >> 6, lane = t & 63;
  int wm = (w >> 1) * 64, wn = (w & 1) * 64;
  bool isV = (n0 >= 1024);
  f32x4 acc[4][4] = {};
  int l3 = lane >> 3;
  int colE = ((lane & 7) ^ l3) * 8;
  const float* aF = x + (int64_t)(m0 + w * 32 + l3) * 1024 + colE;
  const u16* bS = wkvT + (int64_t)(n0 + w * 32 + l3) * 1024 + colE;
  u16* aD = As + w * 2048;
  u16* bD = Bs + w * 2048;
  int l15 = lane & 15, g16 = lane >> 4;
  float4 r0a, r0b, r1a, r1b, r2a, r2b, r3a, r3b;
  r0a = *(const float4*)(aF);             r0b = *(const float4*)(aF + 4);
  r1a = *(const float4*)(aF + 8192);      r1b = *(const float4*)(aF + 8192 + 4);
  r2a = *(const float4*)(aF + 16384);     r2b = *(const float4*)(aF + 16384 + 4);
  r3a = *(const float4*)(aF + 24576);     r3b = *(const float4*)(aF + 24576 + 4);
  for (int kt = 0; kt < 16; ++kt) {
    int ko = kt * 64;
    __syncthreads();
    {
      uint32_t q[4];
#define CVT_WRITE(g, va, vb)                                                   \
      q[0] = cvtpk(va.x, va.y); q[1] = cvtpk(va.z, va.w);                      \
      q[2] = cvtpk(vb.x, vb.y); q[3] = cvtpk(vb.z, vb.w);                      \
      *(bf16x8*)((char*)(aD + (g) * 512) + lane * 16) = *(const bf16x8*)q;
      CVT_WRITE(0, r0a, r0b)
      CVT_WRITE(1, r1a, r1b)
      CVT_WRITE(2, r2a, r2b)
      CVT_WRITE(3, r3a, r3b)
#undef CVT_WRITE
    }
#pragma unroll
    for (int g = 0; g < 4; ++g)
      gload_lds16(bS + ko + g * 8192, bD + g * 512);
    __syncthreads();
    if (kt < 15) {
      int kn = ko + 64;
      r0a = *(const float4*)(aF + kn);          r0b = *(const float4*)(aF + kn + 4);
      r1a = *(const float4*)(aF + kn + 8192);   r1b = *(const float4*)(aF + kn + 8192 + 4);
      r2a = *(const float4*)(aF + kn + 16384);  r2b = *(const float4*)(aF + kn + 16384 + 4);
      r3a = *(const float4*)(aF + kn + 24576);  r3b = *(const float4*)(aF + kn + 24576 + 4);
    }
#pragma unroll
    for (int kk = 0; kk < 2; ++kk) {
      int sl = ((kk * 4 + g16) ^ (l15 & 7)) * 8;
      bf16x8 af[4], bf[4];
#pragma unroll
      for (int i = 0; i < 4; ++i) af[i] = *(const bf16x8*)(As + (wm + i * 16 + l15) * 64 + sl);
#pragma unroll
      for (int j = 0; j < 4; ++j) bf[j] = *(const bf16x8*)(Bs + (wn + j * 16 + l15) * 64 + sl);
      if (!isV) {
#pragma unroll
        for (int i = 0; i < 4; ++i)
#pragma unroll
          for (int j = 0; j < 4; ++j)
            acc[i][j] = __builtin_amdgcn_mfma_f32_16x16x32_bf16(bf[i], af[j], acc[i][j], 0, 0, 0);
      } else {
#pragma unroll
        for (int i = 0; i < 4; ++i)
#pragma unroll
          for (int j = 0; j < 4; ++j)
            acc[i][j] = __builtin_amdgcn_mfma_f32_16x16x32_bf16(af[i], bf[j], acc[i][j], 0, 0, 0);
      }
    }
  }
  int b = m0 >> 11, lbase = m0 & 2047;
  int lr = g16 * 4;
  if (!isV) {
#pragma unroll
    for (int i = 0; i < 4; ++i) {
      int dkg = n0 + wn + i * 16 + lr;
      int h = dkg >> 6, dkk = dkg & 63;
#pragma unroll
      for (int j = 0; j < 4; ++j) {
        int l = lbase + wm + j * 16 + l15;
        u16 p[4];
#pragma unroll
        for (int r = 0; r < 4; ++r) p[r] = f2b(acc[i][j][r]);
        *(uint64_t*)(kbuf + ((int64_t)((b * 16 + h) * 2048 + l)) * 64 + dkk) = *(uint64_t*)p;
      }
    }
  } else {
#pragma unroll
    for (int j = 0; j < 4; ++j) {
      int dvg = (n0 - 1024) + wn + j * 16 + l15;
      int h = dvg >> 6, dv = dvg & 63;
#pragma unroll
      for (int i = 0; i < 4; ++i) {
        int lg = lbase + wm + i * 16 + lr;
        u16 p[4];
#pragma unroll
        for (int r = 0; r < 4; ++r) {
          float val = acc[i][j][r];
          int ll = lg + r;
          if (ll < 30) val *= gate[ll];
          p[r] = f2b(val);
        }
        *(uint64_t*)(vT + ((int64_t)((b * 16 + h) * 64 + dv)) * 2048 + lg) = *(uint64_t*)p;
      }
    }
  }
}

// ---------------- flash attention, L-split x8: block = (b,h,chunk) ----------------
// 4096 blocks (~16/CU): attn is latency-bound (R14: split4 >> split1); double TLP.
__global__ __launch_bounds__(256) void attn_kernel(
    const u16* __restrict__ qb, const u16* __restrict__ kbuf,
    const u16* __restrict__ vT, float* __restrict__ pO,
    float* __restrict__ pm, float* __restrict__ ps) {
  __shared__ u16 Ps[8192];  // per-wave 2 KB (16 rows x 128 B), XOR-swizzled
  int bid = blockIdx.x;
  int b = bid >> 7, h = (bid >> 3) & 15, c = bid & 7;
  int t = threadIdx.x, w = t >> 6, lane = t & 63;
  int l15 = lane & 15, g16 = lane >> 4, lh8 = g16 * 8;
  bf16x8 qf0 = *(const bf16x8*)(qb + (w * 16 + l15) * 1024 + h * 64 + lh8);
  bf16x8 qf1 = *(const bf16x8*)(qb + (w * 16 + l15) * 1024 + h * 64 + 32 + lh8);
  const u16* kB = kbuf + (int64_t)(b * 16 + h) * (2048 * 64);
  const u16* vB = vT + (int64_t)(b * 16 + h) * (64 * 2048);
  char* PsW = (char*)Ps + w * 2048;  // 16 rows x 128 B per wave
  float m_r[4] = {-1e30f, -1e30f, -1e30f, -1e30f};
  float s_r[4] = {0.f, 0.f, 0.f, 0.f};
  f32x4 O[4] = {};
  for (int lt = 0; lt < 4; ++lt) {
    int l0 = c * 256 + lt * 64;
    f32x4 S[4];
#pragma unroll
    for (int ls = 0; ls < 4; ++ls) {
      const u16* kr = kB + (l0 + ls * 16 + l15) * 64 + lh8;
      bf16x8 k0 = *(const bf16x8*)(kr);
      bf16x8 k1 = *(const bf16x8*)(kr + 32);
      f32x4 s = {};
      s = __builtin_amdgcn_mfma_f32_16x16x32_bf16(qf0, k0, s, 0, 0, 0);
      s = __builtin_amdgcn_mfma_f32_16x16x32_bf16(qf1, k1, s, 0, 0, 0);
      S[ls] = s;
    }
    float scale[4];
#pragma unroll
    for (int r = 0; r < 4; ++r) {
      float tm = fmaxf(fmaxf(S[0][r], S[1][r]), fmaxf(S[2][r], S[3][r]));
#pragma unroll
      for (int msk = 1; msk < 16; msk <<= 1)
        tm = fmaxf(tm, __shfl_xor(tm, msk, 16));
      float mn = fmaxf(m_r[r], tm);
      scale[r] = exp2f(m_r[r] - mn);
      m_r[r] = mn;
    }
#pragma unroll
    for (int ls = 0; ls < 4; ++ls)
#pragma unroll
      for (int r = 0; r < 4; ++r) S[ls][r] = exp2f(S[ls][r] - m_r[r]);
#pragma unroll
    for (int r = 0; r < 4; ++r) {
      float psm = (S[0][r] + S[1][r]) + (S[2][r] + S[3][r]);
      s_r[r] = s_r[r] * scale[r] + psm;
    }
#pragma unroll
    for (int ls = 0; ls < 4; ++ls)
#pragma unroll
      for (int r = 0; r < 4; ++r) {
        int row = g16 * 4 + r;
        int off = (ls * 16 + l15) * 2;
        *(u16*)(PsW + row * 128 + (off ^ ((row & 7) << 4))) = f2b(S[ls][r]);
      }
#pragma unroll
    for (int d = 0; d < 4; ++d)
#pragma unroll
      for (int r = 0; r < 4; ++r) O[d][r] *= scale[r];
    bf16x8 pa0, pa1;
    {
      int off0 = g16 * 16;
      pa0 = *(const bf16x8*)(PsW + l15 * 128 + (off0 ^ ((l15 & 7) << 4)));
      pa1 = *(const bf16x8*)(PsW + l15 * 128 + ((off0 + 64) ^ ((l15 & 7) << 4)));
    }
#pragma unroll
    for (int d = 0; d < 4; ++d) {
      const u16* vr = vB + (d * 16 + l15) * 2048 + l0 + lh8;
      bf16x8 v0 = *(const bf16x8*)(vr);
      bf16x8 v1 = *(const bf16x8*)(vr + 32);
      O[d] = __builtin_amdgcn_mfma_f32_16x16x32_bf16(pa0, v0, O[d], 0, 0, 0);
      O[d] = __builtin_amdgcn_mfma_f32_16x16x32_bf16(pa1, v1, O[d], 0, 0, 0);
    }
  }
  // reduce s over the 16-lane group, then store partials
#pragma unroll
  for (int r = 0; r < 4; ++r) {
    float s = s_r[r];
#pragma unroll
    for (int msk = 1; msk < 16; msk <<= 1) s += __shfl_xor(s, msk, 16);
    s_r[r] = s;
  }
  int64_t pbase = (int64_t)bid * 4096;
#pragma unroll
  for (int d = 0; d < 4; ++d)
#pragma unroll
    for (int r = 0; r < 4; ++r) {
      int n = w * 16 + g16 * 4 + r;
      pO[pbase + n * 64 + d * 16 + l15] = O[d][r];
    }
  if (l15 == 0) {
#pragma unroll
    for (int r = 0; r < 4; ++r) {
      int n = w * 16 + g16 * 4 + r;
      pm[bid * 64 + n] = m_r[r];
      ps[bid * 64 + n] = s_r[r];
    }
  }
}

// ---------------- combine 8 L-chunks -> attnout bf16 [2048][1024] ----------------
__global__ __launch_bounds__(256) void attn_combine_kernel(
    const float* __restrict__ pO, const float* __restrict__ pm,
    const float* __restrict__ ps, u16* __restrict__ attnout) {
  int bh = blockIdx.x;  // b*16+h
  int b = bh >> 4, h = bh & 15;
  int t = threadIdx.x;
  int dv = t & 63, grp = t >> 6;
#pragma unroll
  for (int i = 0; i < 16; ++i) {
    int n = grp * 16 + i;
    int base = bh * 512 + n;  // pm idx: (bh*8+c)*64 + n
    float mv[8];
    float M = -1e30f;
#pragma unroll
    for (int cc = 0; cc < 8; ++cc) { mv[cc] = pm[base + cc * 64]; M = fmaxf(M, mv[cc]); }
    float wv[8];
    float stot = 0.f;
#pragma unroll
    for (int cc = 0; cc < 8; ++cc) { wv[cc] = exp2f(mv[cc] - M); stot += wv[cc] * ps[base + cc * 64]; }
    float inv = 1.0f / stot;
    int64_t ob = (int64_t)bh * 32768 + n * 64 + dv;
    float o = 0.f;
#pragma unroll
    for (int cc = 0; cc < 8; ++cc) o += wv[cc] * pO[ob + cc * 4096];
    attnout[((int64_t)(b * 64 + n)) * 1024 + h * 64 + dv] = f2b(o * inv);
  }
}

// ---- FC GEMM [2048 x 1024] @ wfcT + q_tok residual -> fp32 (64x128 tile, 256 blocks) ----
__global__ __launch_bounds__(256, 4) void fc_gemm_kernel(
    const u16* __restrict__ a, const u16* __restrict__ bT,
    const float* __restrict__ q_tok, float* __restrict__ out) {
  __shared__ u16 As[4096];  // [64][64]
  __shared__ u16 Bs[8192];  // [128][64]
  int m0 = (blockIdx.x >> 3) * 64;
  int n0 = (blockIdx.x & 7) * 128;
  int t = threadIdx.x, w = t >> 6, lane = t & 63;
  int wn = w * 32;
  f32x4 acc[2][4] = {};
  int l3 = lane >> 3;
  int colE = ((lane & 7) ^ l3) * 8;
  const u16* aS = a + (int64_t)(m0 + w * 16 + l3) * 1024 + colE;
  const u16* bS = bT + (int64_t)(n0 + w * 32 + l3) * 1024 + colE;
  u16* aD = As + w * 1024;
  u16* bD = Bs + w * 2048;
  int l15 = lane & 15, g16 = lane >> 4;
  for (int kt = 0; kt < 16; ++kt) {
    int ko = kt * 64;
    __syncthreads();
    gload_lds16(aS + ko, aD);
    gload_lds16(aS + ko + 8192, aD + 512);
#pragma unroll
    for (int g = 0; g < 4; ++g) gload_lds16(bS + ko + g * 8192, bD + g * 512);
    __syncthreads();
#pragma unroll
    for (int kk = 0; kk < 2; ++kk) {
      int sl = ((kk * 4 + g16) ^ (l15 & 7)) * 8;
      bf16x8 af[4], bf[2];
#pragma unroll
      for (int j = 0; j < 4; ++j) af[j] = *(const bf16x8*)(As + (j * 16 + l15) * 64 + sl);
#pragma unroll
      for (int i = 0; i < 2; ++i) bf[i] = *(const bf16x8*)(Bs + (wn + i * 16 + l15) * 64 + sl);
#pragma unroll
      for (int i = 0; i < 2; ++i)
#pragma unroll
        for (int j = 0; j < 4; ++j)
          acc[i][j] = __builtin_amdgcn_mfma_f32_16x16x32_bf16(bf[i], af[j], acc[i][j], 0, 0, 0);
    }
  }
  int lr = g16 * 4;
#pragma unroll
  for (int i = 0; i < 2; ++i) {
    int colg = n0 + wn + i * 16 + lr;
#pragma unroll
    for (int j = 0; j < 4; ++j) {
      int row = m0 + j * 16 + l15;
      float4 res = *(const float4*)(q_tok + (row & 63) * 1024 + colg);
      float4 o;
      o.x = acc[i][j][0] + res.x;
      o.y = acc[i][j][1] + res.y;
      o.z = acc[i][j][2] + res.z;
      o.w = acc[i][j][3] + res.w;
      *(float4*)(out + (int64_t)row * 1024 + colg) = o;
    }
  }
}

// ---------------- LayerNorm over last dim (1024), eps=1e-6 ----------------
__global__ __launch_bounds__(256) void ln_kernel(
    const float* __restrict__ fc, const float* __restrict__ gamma,
    const float* __restrict__ beta, float* __restrict__ out) {
  __shared__ float red[8];
  int row = blockIdx.x, t = threadIdx.x;
  float4 y = *(const float4*)(fc + (int64_t)row * 1024 + t * 4);
  float s = (y.x + y.y) + (y.z + y.w);
  float ss = (y.x * y.x + y.y * y.y) + (y.z * y.z + y.w * y.w);
#pragma unroll
  for (int msk = 1; msk < 64; msk <<= 1) {
    s += __shfl_xor(s, msk, 64);
    ss += __shfl_xor(ss, msk, 64);
  }
  if ((t & 63) == 0) { red[t >> 6] = s; red[4 + (t >> 6)] = ss; }
  __syncthreads();
  s = (red[0] + red[1]) + (red[2] + red[3]);
  ss = (red[4] + red[5]) + (red[6] + red[7]);
  float mu = s * (1.0f / 1024.0f);
  float var = ss * (1.0f / 1024.0f) - mu * mu;
  float rstd = rsqrtf(var + 1e-6f);
  float4 g = *(const float4*)(gamma + t * 4);
  float4 be = *(const float4*)(beta + t * 4);
  float4 o;
  o.x = (y.x - mu) * rstd * g.x + be.x;
  o.y = (y.y - mu) * rstd * g.y + be.y;
  o.z = (y.z - mu) * rstd * g.z + be.z;
  o.w = (y.w - mu) * rstd * g.w + be.w;
  *(float4*)(out + (int64_t)row * 1024 + t * 4) = o;
}

extern "C" void kernel_launch(void* const* d_in, const int* in_sizes, int n_in,
                              void* d_out, int out_size, void* d_ws, size_t ws_size,
                              hipStream_t stream) {
  const float* x     = (const float*)d_in[0];
  const float* q_tok = (const float*)d_in[1];
  const float* Wq    = (const float*)d_in[2];
  const float* Wk    = (const float*)d_in[3];
  const float* Wv    = (const float*)d_in[4];
  const float* Wfc   = (const float*)d_in[5];
  const float* gl    = (const float*)d_in[6];
  const float* gamma = (const float*)d_in[7];
  const float* beta  = (const float*)d_in[8];
  float* out = (float*)d_out;
  char* ws = (char*)d_ws;

  u16*   kbuf    = (u16*)(ws + 134217728);        // 134 MB [B][H][L][64]
  u16*   vT      = (u16*)(ws + 268435456);        // 134 MB [B][H][64][L]
  u16*   wkvT    = (u16*)(ws + 402653184);        // 4 MB
  u16*   wfcT    = (u16*)(ws + 406847488);        // 2 MB
  u16*   wqT     = (u16*)(ws + 408944640);        // 2 MB
  u16*   qtokb   = (u16*)(ws + 411041792);        // 128 KB
  u16*   qb      = (u16*)(ws + 411172864);        // 128 KB [64][1024]
  float* gate    = (float*)(ws + 411303936);      // 512 B
  u16*   attnout = (u16*)(ws + 411304448);        // 4 MB
  float* fcout   = (float*)(ws + 415498752);      // 8 MB
  // first 134 MB region is free (no xb since cvt fusion): attn partials live there
  float* pO = (float*)(ws);                       // 67,108,864 B  [4096 blk][4096]
  float* pm = (float*)(ws + 67108864);            // 1,048,576 B   [4096 blk][64]
  float* ps = (float*)(ws + 68157440);            // 1,048,576 B   [4096 blk][64]

  transpose_all_kernel<<<1024, 256, 0, stream>>>(Wk, Wv, Wfc, Wq, wkvT, wfcT, wqT, gl, gate);
  cvt_kernel<<<32, 256, 0, stream>>>(q_tok, qtokb, 8192); // 64K elems / 8
  q_gemm_kernel<<<8, 256, 0, stream>>>(qtokb, wqT, qb);
  kv_gemm_kernel<<<8192, 256, 0, stream>>>(x, wkvT, gate, kbuf, vT);
  attn_kernel<<<4096, 256, 0, stream>>>(qb, kbuf, vT, pO, pm, ps);
  attn_combine_kernel<<<512, 256, 0, stream>>>(pO, pm, ps, attnout);
  fc_gemm_kernel<<<256, 256, 0, stream>>>(attnout, wfcT, q_tok, fcout);
  ln_kernel<<<2048, 256, 0, stream>>>(fcout, gamma, beta, out);
}

// Round 18
// 646.538 us; speedup vs baseline: 1.0329x; 1.0329x over previous
//
#include <hip/hip_runtime.h>
#include <stdint.h>

typedef unsigned short u16;
typedef short bf16x8 __attribute__((ext_vector_type(8)));
typedef float f32x4 __attribute__((ext_vector_type(4)));

__device__ __forceinline__ u16 f2b(float f) {
  uint32_t u = __builtin_bit_cast(uint32_t, f);
  u += 0x7fffu + ((u >> 16) & 1u);
  return (u16)(u >> 16);
}

// 2x f32 -> packed 2x bf16 (RNE), single VALU op (gfx950). lo -> bits[15:0].
__device__ __forceinline__ uint32_t cvtpk(float lo, float hi) {
  uint32_t r;
  asm("v_cvt_pk_bf16_f32 %0, %1, %2" : "=v"(r) : "v"(lo), "v"(hi));
  return r;
}

__device__ __forceinline__ void gload_lds16(const void* g, void* l) {
  __builtin_amdgcn_global_load_lds(
      (const __attribute__((address_space(1))) void*)g,
      (__attribute__((address_space(3))) void*)l, 16, 0, 0);
}

// ---------------- fp32 -> bf16, grid-stride (total elems = n8 * 8) ----------------
__global__ __launch_bounds__(256) void cvt_kernel(const float* __restrict__ src,
                                                  u16* __restrict__ dst, int n8) {
  int stride = gridDim.x * 256;
  for (int idx = blockIdx.x * 256 + threadIdx.x; idx < n8; idx += stride) {
    int64_t i = (int64_t)idx * 8;
    float4 a = *(const float4*)(src + i);
    float4 b = *(const float4*)(src + i + 4);
    union { u16 u[8]; bf16x8 v; } o;
    o.u[0] = f2b(a.x); o.u[1] = f2b(a.y); o.u[2] = f2b(a.z); o.u[3] = f2b(a.w);
    o.u[4] = f2b(b.x); o.u[5] = f2b(b.y); o.u[6] = f2b(b.z); o.u[7] = f2b(b.w);
    *(bf16x8*)(dst + i) = o.v;
  }
}

// ---- merged: 4x W [1024][1024] fp32 -> W^T bf16 (+ gate cumprod on block 0) ----
__global__ __launch_bounds__(256) void transpose_all_kernel(
    const float* __restrict__ Wk, const float* __restrict__ Wv,
    const float* __restrict__ Wfc, const float* __restrict__ Wq,
    u16* __restrict__ wkvT, u16* __restrict__ wfcT, u16* __restrict__ wqT,
    const float* __restrict__ gl, float* __restrict__ gate) {
  if (blockIdx.x == 0 && threadIdx.x == 0) {
    float g = 1.0f;
    for (int i = 0; i < 30; ++i) {
      float s = 1.0f / (1.0f + __expf(-gl[i]));
      g *= (1.0f - s);
      gate[i] = g;
    }
  }
  __shared__ float ls[64][65];
  int which = blockIdx.x >> 8;
  int tile = blockIdx.x & 255;
  const float* src = (which == 0) ? Wk : (which == 1) ? Wv : (which == 2) ? Wfc : Wq;
  u16* dst = (which == 0) ? wkvT : (which == 1) ? (wkvT + 1024 * 1024)
           : (which == 2) ? wfcT : wqT;
  int t = threadIdx.x;
  int bx = tile & 15;
  int by = tile >> 4;
  int r0 = by * 64, c0 = bx * 64;
  int tr = t >> 6, tc = t & 63;
#pragma unroll
  for (int i = 0; i < 16; ++i)
    ls[tr + i * 4][tc] = src[(int64_t)(r0 + tr + i * 4) * 1024 + c0 + tc];
  __syncthreads();
#pragma unroll
  for (int i = 0; i < 16; ++i)
    dst[(int64_t)(c0 + tr + i * 4) * 1024 + r0 + tc] = f2b(ls[tc][tr + i * 4]);
}

// ---------------- q GEMM: [64 x 1024] @ wqT -> qb [64][1024] (scaled) ----------------
__global__ __launch_bounds__(256, 4) void q_gemm_kernel(
    const u16* __restrict__ qtokb, const u16* __restrict__ wqT, u16* __restrict__ qb) {
  __shared__ u16 As[4096];  // [64][64]
  __shared__ u16 Bs[8192];  // [128][64]
  int n0 = blockIdx.x * 128;
  int t = threadIdx.x, w = t >> 6, lane = t & 63;
  int wn = w * 32;
  f32x4 acc[2][4] = {};
  int l3 = lane >> 3;
  int colE = ((lane & 7) ^ l3) * 8;
  const u16* aS = qtokb + (int64_t)(w * 16 + l3) * 1024 + colE;
  const u16* bS = wqT + (int64_t)(n0 + w * 32 + l3) * 1024 + colE;
  u16* aD = As + w * 1024;
  u16* bD = Bs + w * 2048;
  int l15 = lane & 15, g16 = lane >> 4;
  for (int kt = 0; kt < 16; ++kt) {
    int ko = kt * 64;
    __syncthreads();
    gload_lds16(aS + ko, aD);
    gload_lds16(aS + ko + 8192, aD + 512);
#pragma unroll
    for (int g = 0; g < 4; ++g) gload_lds16(bS + ko + g * 8192, bD + g * 512);
    __syncthreads();
#pragma unroll
    for (int kk = 0; kk < 2; ++kk) {
      int sl = ((kk * 4 + g16) ^ (l15 & 7)) * 8;
      bf16x8 af[4], bf[2];
#pragma unroll
      for (int j = 0; j < 4; ++j) af[j] = *(const bf16x8*)(As + (j * 16 + l15) * 64 + sl);
#pragma unroll
      for (int i = 0; i < 2; ++i) bf[i] = *(const bf16x8*)(Bs + (wn + i * 16 + l15) * 64 + sl);
#pragma unroll
      for (int i = 0; i < 2; ++i)
#pragma unroll
        for (int j = 0; j < 4; ++j)
          acc[i][j] = __builtin_amdgcn_mfma_f32_16x16x32_bf16(bf[i], af[j], acc[i][j], 0, 0, 0);
    }
  }
  const float sc = 1.44269504f / 8.0f;  // log2e / sqrt(dk)
  int lr = g16 * 4;
#pragma unroll
  for (int i = 0; i < 2; ++i) {
    int colg = n0 + wn + i * 16 + lr;
#pragma unroll
    for (int j = 0; j < 4; ++j) {
      int qrow = j * 16 + l15;
      u16 p[4];
#pragma unroll
      for (int r = 0; r < 4; ++r) p[r] = f2b(acc[i][j][r] * sc);
      *(uint64_t*)(qb + qrow * 1024 + colg) = *(uint64_t*)p;
    }
  }
}

// ---------------- KV GEMM (cvt-fused): [65536 x 1024 fp32] @ [1024 x 2048] ----------------
// Final structure (~500 us): A reg-staged with v_cvt_pk_bf16_f32 (T14 issue-early),
// B gload_lds, XCD-grouped mapping, (256,2). Latency-bound plateau; all local
// pipelining/occupancy/mapping variants measured and regressed (R7-R12).
__global__ __launch_bounds__(256, 2) void kv_gemm_kernel(
    const float* __restrict__ x, const u16* __restrict__ wkvT,
    const float* __restrict__ gate, u16* __restrict__ kbuf, u16* __restrict__ vT) {
  __shared__ u16 As[8192];  // [128][64]
  __shared__ u16 Bs[8192];
  int d = blockIdx.x;
  int xc = d & 7;
  int nb = (d >> 3) & 15;
  int mb = (d >> 7) * 8 + xc;
  int m0 = mb * 128, n0 = nb * 128;
  int t = threadIdx.x, w = t >> 6, lane = t & 63;
  int wm = (w >> 1) * 64, wn = (w & 1) * 64;
  bool isV = (n0 >= 1024);
  f32x4 acc[4][4] = {};
  int l3 = lane >> 3;
  int colE = ((lane & 7) ^ l3) * 8;
  const float* aF = x + (int64_t)(m0 + w * 32 + l3) * 1024 + colE;
  const u16* bS = wkvT + (int64_t)(n0 + w * 32 + l3) * 1024 + colE;
  u16* aD = As + w * 2048;
  u16* bD = Bs + w * 2048;
  int l15 = lane & 15, g16 = lane >> 4;
  float4 r0a, r0b, r1a, r1b, r2a, r2b, r3a, r3b;
  r0a = *(const float4*)(aF);             r0b = *(const float4*)(aF + 4);
  r1a = *(const float4*)(aF + 8192);      r1b = *(const float4*)(aF + 8192 + 4);
  r2a = *(const float4*)(aF + 16384);     r2b = *(const float4*)(aF + 16384 + 4);
  r3a = *(const float4*)(aF + 24576);     r3b = *(const float4*)(aF + 24576 + 4);
  for (int kt = 0; kt < 16; ++kt) {
    int ko = kt * 64;
    __syncthreads();
    {
      uint32_t q[4];
#define CVT_WRITE(g, va, vb)                                                   \
      q[0] = cvtpk(va.x, va.y); q[1] = cvtpk(va.z, va.w);                      \
      q[2] = cvtpk(vb.x, vb.y); q[3] = cvtpk(vb.z, vb.w);                      \
      *(bf16x8*)((char*)(aD + (g) * 512) + lane * 16) = *(const bf16x8*)q;
      CVT_WRITE(0, r0a, r0b)
      CVT_WRITE(1, r1a, r1b)
      CVT_WRITE(2, r2a, r2b)
      CVT_WRITE(3, r3a, r3b)
#undef CVT_WRITE
    }
#pragma unroll
    for (int g = 0; g < 4; ++g)
      gload_lds16(bS + ko + g * 8192, bD + g * 512);
    __syncthreads();
    if (kt < 15) {
      int kn = ko + 64;
      r0a = *(const float4*)(aF + kn);          r0b = *(const float4*)(aF + kn + 4);
      r1a = *(const float4*)(aF + kn + 8192);   r1b = *(const float4*)(aF + kn + 8192 + 4);
      r2a = *(const float4*)(aF + kn + 16384);  r2b = *(const float4*)(aF + kn + 16384 + 4);
      r3a = *(const float4*)(aF + kn + 24576);  r3b = *(const float4*)(aF + kn + 24576 + 4);
    }
#pragma unroll
    for (int kk = 0; kk < 2; ++kk) {
      int sl = ((kk * 4 + g16) ^ (l15 & 7)) * 8;
      bf16x8 af[4], bf[4];
#pragma unroll
      for (int i = 0; i < 4; ++i) af[i] = *(const bf16x8*)(As + (wm + i * 16 + l15) * 64 + sl);
#pragma unroll
      for (int j = 0; j < 4; ++j) bf[j] = *(const bf16x8*)(Bs + (wn + j * 16 + l15) * 64 + sl);
      if (!isV) {
#pragma unroll
        for (int i = 0; i < 4; ++i)
#pragma unroll
          for (int j = 0; j < 4; ++j)
            acc[i][j] = __builtin_amdgcn_mfma_f32_16x16x32_bf16(bf[i], af[j], acc[i][j], 0, 0, 0);
      } else {
#pragma unroll
        for (int i = 0; i < 4; ++i)
#pragma unroll
          for (int j = 0; j < 4; ++j)
            acc[i][j] = __builtin_amdgcn_mfma_f32_16x16x32_bf16(af[i], bf[j], acc[i][j], 0, 0, 0);
      }
    }
  }
  int b = m0 >> 11, lbase = m0 & 2047;
  int lr = g16 * 4;
  if (!isV) {
#pragma unroll
    for (int i = 0; i < 4; ++i) {
      int dkg = n0 + wn + i * 16 + lr;
      int h = dkg >> 6, dkk = dkg & 63;
#pragma unroll
      for (int j = 0; j < 4; ++j) {
        int l = lbase + wm + j * 16 + l15;
        u16 p[4];
#pragma unroll
        for (int r = 0; r < 4; ++r) p[r] = f2b(acc[i][j][r]);
        *(uint64_t*)(kbuf + ((int64_t)((b * 16 + h) * 2048 + l)) * 64 + dkk) = *(uint64_t*)p;
      }
    }
  } else {
#pragma unroll
    for (int j = 0; j < 4; ++j) {
      int dvg = (n0 - 1024) + wn + j * 16 + l15;
      int h = dvg >> 6, dv = dvg & 63;
#pragma unroll
      for (int i = 0; i < 4; ++i) {
        int lg = lbase + wm + i * 16 + lr;
        u16 p[4];
#pragma unroll
        for (int r = 0; r < 4; ++r) {
          float val = acc[i][j][r];
          int ll = lg + r;
          if (ll < 30) val *= gate[ll];
          p[r] = f2b(val);
        }
        *(uint64_t*)(vT + ((int64_t)((b * 16 + h) * 64 + dv)) * 2048 + lg) = *(uint64_t*)p;
      }
    }
  }
}

// ---------------- flash attention, L-split x4: block = (b,h,chunk) ----------------
// Split=4 is the measured optimum of {1,4,8} (R14: 1 too little TLP; R17: 8 too
// much partial traffic).
__global__ __launch_bounds__(256) void attn_kernel(
    const u16* __restrict__ qb, const u16* __restrict__ kbuf,
    const u16* __restrict__ vT, float* __restrict__ pO,
    float* __restrict__ pm, float* __restrict__ ps) {
  __shared__ u16 Ps[8192];  // per-wave 2 KB (16 rows x 128 B), XOR-swizzled
  int bid = blockIdx.x;
  int b = bid >> 6, h = (bid >> 2) & 15, c = bid & 3;
  int t = threadIdx.x, w = t >> 6, lane = t & 63;
  int l15 = lane & 15, g16 = lane >> 4, lh8 = g16 * 8;
  bf16x8 qf0 = *(const bf16x8*)(qb + (w * 16 + l15) * 1024 + h * 64 + lh8);
  bf16x8 qf1 = *(const bf16x8*)(qb + (w * 16 + l15) * 1024 + h * 64 + 32 + lh8);
  const u16* kB = kbuf + (int64_t)(b * 16 + h) * (2048 * 64);
  const u16* vB = vT + (int64_t)(b * 16 + h) * (64 * 2048);
  char* PsW = (char*)Ps + w * 2048;  // 16 rows x 128 B per wave
  float m_r[4] = {-1e30f, -1e30f, -1e30f, -1e30f};
  float s_r[4] = {0.f, 0.f, 0.f, 0.f};
  f32x4 O[4] = {};
  for (int lt = 0; lt < 8; ++lt) {
    int l0 = c * 512 + lt * 64;
    f32x4 S[4];
#pragma unroll
    for (int ls = 0; ls < 4; ++ls) {
      const u16* kr = kB + (l0 + ls * 16 + l15) * 64 + lh8;
      bf16x8 k0 = *(const bf16x8*)(kr);
      bf16x8 k1 = *(const bf16x8*)(kr + 32);
      f32x4 s = {};
      s = __builtin_amdgcn_mfma_f32_16x16x32_bf16(qf0, k0, s, 0, 0, 0);
      s = __builtin_amdgcn_mfma_f32_16x16x32_bf16(qf1, k1, s, 0, 0, 0);
      S[ls] = s;
    }
    float scale[4];
#pragma unroll
    for (int r = 0; r < 4; ++r) {
      float tm = fmaxf(fmaxf(S[0][r], S[1][r]), fmaxf(S[2][r], S[3][r]));
#pragma unroll
      for (int msk = 1; msk < 16; msk <<= 1)
        tm = fmaxf(tm, __shfl_xor(tm, msk, 16));
      float mn = fmaxf(m_r[r], tm);
      scale[r] = exp2f(m_r[r] - mn);
      m_r[r] = mn;
    }
#pragma unroll
    for (int ls = 0; ls < 4; ++ls)
#pragma unroll
      for (int r = 0; r < 4; ++r) S[ls][r] = exp2f(S[ls][r] - m_r[r]);
#pragma unroll
    for (int r = 0; r < 4; ++r) {
      float psm = (S[0][r] + S[1][r]) + (S[2][r] + S[3][r]);
      s_r[r] = s_r[r] * scale[r] + psm;
    }
#pragma unroll
    for (int ls = 0; ls < 4; ++ls)
#pragma unroll
      for (int r = 0; r < 4; ++r) {
        int row = g16 * 4 + r;
        int off = (ls * 16 + l15) * 2;
        *(u16*)(PsW + row * 128 + (off ^ ((row & 7) << 4))) = f2b(S[ls][r]);
      }
#pragma unroll
    for (int d = 0; d < 4; ++d)
#pragma unroll
      for (int r = 0; r < 4; ++r) O[d][r] *= scale[r];
    bf16x8 pa0, pa1;
    {
      int off0 = g16 * 16;
      pa0 = *(const bf16x8*)(PsW + l15 * 128 + (off0 ^ ((l15 & 7) << 4)));
      pa1 = *(const bf16x8*)(PsW + l15 * 128 + ((off0 + 64) ^ ((l15 & 7) << 4)));
    }
#pragma unroll
    for (int d = 0; d < 4; ++d) {
      const u16* vr = vB + (d * 16 + l15) * 2048 + l0 + lh8;
      bf16x8 v0 = *(const bf16x8*)(vr);
      bf16x8 v1 = *(const bf16x8*)(vr + 32);
      O[d] = __builtin_amdgcn_mfma_f32_16x16x32_bf16(pa0, v0, O[d], 0, 0, 0);
      O[d] = __builtin_amdgcn_mfma_f32_16x16x32_bf16(pa1, v1, O[d], 0, 0, 0);
    }
  }
  // reduce s over the 16-lane group, then store partials
#pragma unroll
  for (int r = 0; r < 4; ++r) {
    float s = s_r[r];
#pragma unroll
    for (int msk = 1; msk < 16; msk <<= 1) s += __shfl_xor(s, msk, 16);
    s_r[r] = s;
  }
  int64_t pbase = (int64_t)bid * 4096;
#pragma unroll
  for (int d = 0; d < 4; ++d)
#pragma unroll
    for (int r = 0; r < 4; ++r) {
      int n = w * 16 + g16 * 4 + r;
      pO[pbase + n * 64 + d * 16 + l15] = O[d][r];
    }
  if (l15 == 0) {
#pragma unroll
    for (int r = 0; r < 4; ++r) {
      int n = w * 16 + g16 * 4 + r;
      pm[bid * 64 + n] = m_r[r];
      ps[bid * 64 + n] = s_r[r];
    }
  }
}

// ---------------- combine 4 L-chunks -> attnout bf16 [2048][1024] ----------------
__global__ __launch_bounds__(256) void attn_combine_kernel(
    const float* __restrict__ pO, const float* __restrict__ pm,
    const float* __restrict__ ps, u16* __restrict__ attnout) {
  int bh = blockIdx.x;  // b*16+h
  int b = bh >> 4, h = bh & 15;
  int t = threadIdx.x;
  int dv = t & 63, grp = t >> 6;
#pragma unroll
  for (int i = 0; i < 16; ++i) {
    int n = grp * 16 + i;
    int base = bh * 256 + n;  // pm idx: (bh*4+c)*64 + n
    float m0 = pm[base], m1 = pm[base + 64], m2 = pm[base + 128], m3 = pm[base + 192];
    float M = fmaxf(fmaxf(m0, m1), fmaxf(m2, m3));
    float w0 = exp2f(m0 - M), w1 = exp2f(m1 - M), w2 = exp2f(m2 - M), w3 = exp2f(m3 - M);
    float stot = w0 * ps[base] + w1 * ps[base + 64] + w2 * ps[base + 128] + w3 * ps[base + 192];
    float inv = 1.0f / stot;
    int64_t ob = (int64_t)bh * 16384 + n * 64 + dv;
    float o = w0 * pO[ob] + w1 * pO[ob + 4096] + w2 * pO[ob + 8192] + w3 * pO[ob + 12288];
    attnout[((int64_t)(b * 64 + n)) * 1024 + h * 64 + dv] = f2b(o * inv);
  }
}

// ---- FC GEMM [2048 x 1024] @ wfcT + q_tok residual -> fp32 (64x128 tile, 256 blocks) ----
__global__ __launch_bounds__(256, 4) void fc_gemm_kernel(
    const u16* __restrict__ a, const u16* __restrict__ bT,
    const float* __restrict__ q_tok, float* __restrict__ out) {
  __shared__ u16 As[4096];  // [64][64]
  __shared__ u16 Bs[8192];  // [128][64]
  int m0 = (blockIdx.x >> 3) * 64;
  int n0 = (blockIdx.x & 7) * 128;
  int t = threadIdx.x, w = t >> 6, lane = t & 63;
  int wn = w * 32;
  f32x4 acc[2][4] = {};
  int l3 = lane >> 3;
  int colE = ((lane & 7) ^ l3) * 8;
  const u16* aS = a + (int64_t)(m0 + w * 16 + l3) * 1024 + colE;
  const u16* bS = bT + (int64_t)(n0 + w * 32 + l3) * 1024 + colE;
  u16* aD = As + w * 1024;
  u16* bD = Bs + w * 2048;
  int l15 = lane & 15, g16 = lane >> 4;
  for (int kt = 0; kt < 16; ++kt) {
    int ko = kt * 64;
    __syncthreads();
    gload_lds16(aS + ko, aD);
    gload_lds16(aS + ko + 8192, aD + 512);
#pragma unroll
    for (int g = 0; g < 4; ++g) gload_lds16(bS + ko + g * 8192, bD + g * 512);
    __syncthreads();
#pragma unroll
    for (int kk = 0; kk < 2; ++kk) {
      int sl = ((kk * 4 + g16) ^ (l15 & 7)) * 8;
      bf16x8 af[4], bf[2];
#pragma unroll
      for (int j = 0; j < 4; ++j) af[j] = *(const bf16x8*)(As + (j * 16 + l15) * 64 + sl);
#pragma unroll
      for (int i = 0; i < 2; ++i) bf[i] = *(const bf16x8*)(Bs + (wn + i * 16 + l15) * 64 + sl);
#pragma unroll
      for (int i = 0; i < 2; ++i)
#pragma unroll
        for (int j = 0; j < 4; ++j)
          acc[i][j] = __builtin_amdgcn_mfma_f32_16x16x32_bf16(bf[i], af[j], acc[i][j], 0, 0, 0);
    }
  }
  int lr = g16 * 4;
#pragma unroll
  for (int i = 0; i < 2; ++i) {
    int colg = n0 + wn + i * 16 + lr;
#pragma unroll
    for (int j = 0; j < 4; ++j) {
      int row = m0 + j * 16 + l15;
      float4 res = *(const float4*)(q_tok + (row & 63) * 1024 + colg);
      float4 o;
      o.x = acc[i][j][0] + res.x;
      o.y = acc[i][j][1] + res.y;
      o.z = acc[i][j][2] + res.z;
      o.w = acc[i][j][3] + res.w;
      *(float4*)(out + (int64_t)row * 1024 + colg) = o;
    }
  }
}

// ---------------- LayerNorm over last dim (1024), eps=1e-6 ----------------
__global__ __launch_bounds__(256) void ln_kernel(
    const float* __restrict__ fc, const float* __restrict__ gamma,
    const float* __restrict__ beta, float* __restrict__ out) {
  __shared__ float red[8];
  int row = blockIdx.x, t = threadIdx.x;
  float4 y = *(const float4*)(fc + (int64_t)row * 1024 + t * 4);
  float s = (y.x + y.y) + (y.z + y.w);
  float ss = (y.x * y.x + y.y * y.y) + (y.z * y.z + y.w * y.w);
#pragma unroll
  for (int msk = 1; msk < 64; msk <<= 1) {
    s += __shfl_xor(s, msk, 64);
    ss += __shfl_xor(ss, msk, 64);
  }
  if ((t & 63) == 0) { red[t >> 6] = s; red[4 + (t >> 6)] = ss; }
  __syncthreads();
  s = (red[0] + red[1]) + (red[2] + red[3]);
  ss = (red[4] + red[5]) + (red[6] + red[7]);
  float mu = s * (1.0f / 1024.0f);
  float var = ss * (1.0f / 1024.0f) - mu * mu;
  float rstd = rsqrtf(var + 1e-6f);
  float4 g = *(const float4*)(gamma + t * 4);
  float4 be = *(const float4*)(beta + t * 4);
  float4 o;
  o.x = (y.x - mu) * rstd * g.x + be.x;
  o.y = (y.y - mu) * rstd * g.y + be.y;
  o.z = (y.z - mu) * rstd * g.z + be.z;
  o.w = (y.w - mu) * rstd * g.w + be.w;
  *(float4*)(out + (int64_t)row * 1024 + t * 4) = o;
}

extern "C" void kernel_launch(void* const* d_in, const int* in_sizes, int n_in,
                              void* d_out, int out_size, void* d_ws, size_t ws_size,
                              hipStream_t stream) {
  const float* x     = (const float*)d_in[0];
  const float* q_tok = (const float*)d_in[1];
  const float* Wq    = (const float*)d_in[2];
  const float* Wk    = (const float*)d_in[3];
  const float* Wv    = (const float*)d_in[4];
  const float* Wfc   = (const float*)d_in[5];
  const float* gl    = (const float*)d_in[6];
  const float* gamma = (const float*)d_in[7];
  const float* beta  = (const float*)d_in[8];
  float* out = (float*)d_out;
  char* ws = (char*)d_ws;

  u16*   kbuf    = (u16*)(ws + 134217728);        // 134 MB [B][H][L][64]
  u16*   vT      = (u16*)(ws + 268435456);        // 134 MB [B][H][64][L]
  u16*   wkvT    = (u16*)(ws + 402653184);        // 4 MB
  u16*   wfcT    = (u16*)(ws + 406847488);        // 2 MB
  u16*   wqT     = (u16*)(ws + 408944640);        // 2 MB
  u16*   qtokb   = (u16*)(ws + 411041792);        // 128 KB
  u16*   qb      = (u16*)(ws + 411172864);        // 128 KB [64][1024]
  float* gate    = (float*)(ws + 411303936);      // 512 B
  u16*   attnout = (u16*)(ws + 411304448);        // 4 MB
  float* fcout   = (float*)(ws + 415498752);      // 8 MB
  // first 134 MB region is free (no xb since cvt fusion): attn partials live there
  float* pO = (float*)(ws);                       // 33,554,432 B  [2048 blk][4096]
  float* pm = (float*)(ws + 33554432);            // 524,288 B     [2048 blk][64]
  float* ps = (float*)(ws + 34078720);            // 524,288 B     [2048 blk][64]

  transpose_all_kernel<<<1024, 256, 0, stream>>>(Wk, Wv, Wfc, Wq, wkvT, wfcT, wqT, gl, gate);
  cvt_kernel<<<32, 256, 0, stream>>>(q_tok, qtokb, 8192); // 64K elems / 8
  q_gemm_kernel<<<8, 256, 0, stream>>>(qtokb, wqT, qb);
  kv_gemm_kernel<<<8192, 256, 0, stream>>>(x, wkvT, gate, kbuf, vT);
  attn_kernel<<<2048, 256, 0, stream>>>(qb, kbuf, vT, pO, pm, ps);
  attn_combine_kernel<<<512, 256, 0, stream>>>(pO, pm, ps, attnout);
  fc_gemm_kernel<<<256, 256, 0, stream>>>(attnout, wfcT, q_tok, fcout);
  ln_kernel<<<2048, 256, 0, stream>>>(fcout, gamma, beta, out);
}